// Round 9
// baseline (336.374 us; speedup 1.0000x reference)
//
#include <hip/hip_runtime.h>

// SoftClusterGaussianHead — fused two-phase kernel, DPP-shortened reductions.
// B=8, N=4096, D=512, K=8.
// sigma = S2 + (S0-2)*S1^2 with S0=sum_n p, S1=sum_n p*x, S2=sum_n p*x^2.
// Phase 1: logits -> reduce-scatter to k-pairs. Cross-lane hops via DPP
//   (quad_perm xor1/xor2, row_ror 4/8) at VALU latency; only xor16/xor32 are
//   DS ops. Lane-local softmax via quad_perm. p -> LDS (1 KB).
// Phase 2: wave owns k-pair {w, w+4}, 2-row ILP + prefetch, coalesced flush.
// ws: partial[b][chunk][k][d][2] | s0p[b][chunk][k]

typedef float v2f __attribute__((ext_vector_type(2)));

#define B_ 8
#define N_ 4096
#define D_ 512
#define K_ 8
#define EPS_ 1e-6f
#define CHUNKS 128           // blocks per b
#define ROWS_PB 32           // rows per block
#define PART_FLOATS(cs) ((size_t)B_ * (cs) * K_ * D_ * 2)
#define S0_FLOATS(cs)   ((size_t)B_ * (cs) * K_)

template <int CTRL>
__device__ __forceinline__ float dppf(float v) {
  int i = __float_as_int(v);
  return __int_as_float(__builtin_amdgcn_update_dpp(i, i, CTRL, 0xF, 0xF, false));
}
#define DPP_XOR1 0xB1   // quad_perm(1,0,3,2)
#define DPP_XOR2 0x4E   // quad_perm(2,3,0,1)
#define DPP_ROR4 0x124  // row_ror:4
#define DPP_ROR8 0x128  // row_ror:8

__global__ __launch_bounds__(256, 2)
void k1_fused(const float* __restrict__ x, const float* __restrict__ W,
              const float* __restrict__ bias, float* __restrict__ partial,
              float* __restrict__ s0p, float* __restrict__ out,
              int cstride, int atomic_mode) {
#pragma clang fp contract(fast)
  const int lane = threadIdx.x & 63;
  const int wave = threadIdx.x >> 6;    // 0..3
  const int b     = blockIdx.x >> 7;
  const int chunk = blockIdx.x & 127;

  // zero the KL accumulator slot for k2 (k1 fully precedes k2 in-stream)
  if (blockIdx.x == 0 && threadIdx.x == 0) out[B_ * D_] = 0.f;

  // p_lds[row][2*kq + sel]: (p[kq], p[kq+4]) pairs, kq = 0..3
  __shared__ float p_lds[ROWS_PB][K_];   // 1 KB
  __shared__ v2f   s0sh[4][4];           // [wave][kq] = (S0_k, S0_k+4)

  const float* xb = x + ((size_t)b * N_ + (size_t)chunk * ROWS_PB) * D_;

  // ---------------- phase 1: softmax probs ----------------
  {
    // lane owns d = 8*lane .. 8*lane+7 ; wk[dj][kp] = (W[d][2kp], W[d][2kp+1])
    v2f wk[8][4];
#pragma unroll
    for (int dj = 0; dj < 8; ++dj) {
      const float4* wr = reinterpret_cast<const float4*>(&W[(8 * lane + dj) * K_]);
      float4 wa = wr[0], wb4 = wr[1];
      wk[dj][0] = (v2f){wa.x, wa.y};   wk[dj][1] = (v2f){wa.z, wa.w};
      wk[dj][2] = (v2f){wb4.x, wb4.y}; wk[dj][3] = (v2f){wb4.z, wb4.w};
    }
    const int kq = lane & 3;
    const v2f biasv2 = (v2f){bias[kq], bias[kq + 4]};
    const bool cb0 = (lane & 1) != 0;
    const bool cb1 = (lane & 2) != 0;

    auto row_probs = [&](float4 xa, float4 xc) -> v2f {
      float xv[8] = {xa.x, xa.y, xa.z, xa.w, xc.x, xc.y, xc.z, xc.w};
      v2f qp[4] = {(v2f){0,0},(v2f){0,0},(v2f){0,0},(v2f){0,0}};
#pragma unroll
      for (int dj = 0; dj < 8; ++dj) {
        v2f xx = (v2f){xv[dj], xv[dj]};
#pragma unroll
        for (int kp = 0; kp < 4; ++kp) qp[kp] += wk[dj][kp] * xx;
      }
      float q0=qp[0].x,q1=qp[0].y,q2=qp[1].x,q3=qp[1].y;
      float q4=qp[2].x,q5=qp[2].y,q6=qp[3].x,q7=qp[3].y;

      // stage A (xor1 via quad_perm): combine q-pairs
      float r0 = cb0 ? q0 : q1, r1 = cb0 ? q2 : q3, r2 = cb0 ? q4 : q5, r3 = cb0 ? q6 : q7;
      r0 = dppf<DPP_XOR1>(r0); r1 = dppf<DPP_XOR1>(r1);
      r2 = dppf<DPP_XOR1>(r2); r3 = dppf<DPP_XOR1>(r3);
      float a0 = (cb0 ? q1 : q0) + r0, a1 = (cb0 ? q3 : q2) + r1;
      float a2 = (cb0 ? q5 : q4) + r2, a3 = (cb0 ? q7 : q6) + r3;
      // stage B (xor2 via quad_perm): lane ends with (k=kq, k=kq+4) partial
      float s0_ = cb1 ? a0 : a1, s1_ = cb1 ? a2 : a3;
      s0_ = dppf<DPP_XOR2>(s0_); s1_ = dppf<DPP_XOR2>(s1_);
      v2f t2 = (v2f){(cb1 ? a1 : a0) + s0_, (cb1 ? a3 : a2) + s1_};
      // stage C: sum same-kq lanes. ror4+ror8 (DPP, class-preserving mod 4),
      // then cross-row xor16, cross-half xor32 (the only DS-latency hops).
      t2.x += dppf<DPP_ROR4>(t2.x); t2.y += dppf<DPP_ROR4>(t2.y);
      t2.x += dppf<DPP_ROR8>(t2.x); t2.y += dppf<DPP_ROR8>(t2.y);
      t2.x += __shfl_xor(t2.x, 16, 64); t2.y += __shfl_xor(t2.y, 16, 64);
      t2.x += __shfl_xor(t2.x, 32, 64); t2.y += __shfl_xor(t2.y, 32, 64);
      t2 += biasv2;
      // softmax over 8 k's within the quad (all DPP)
      float mx = fmaxf(t2.x, t2.y);
      mx = fmaxf(mx, dppf<DPP_XOR1>(mx));
      mx = fmaxf(mx, dppf<DPP_XOR2>(mx));
      float ex = __expf(t2.x - mx), ey = __expf(t2.y - mx);
      float se = ex + ey;
      se += dppf<DPP_XOR1>(se);
      se += dppf<DPP_XOR2>(se);
      float inv = __builtin_amdgcn_rcpf(se);
      return (v2f){ex * inv, ey * inv};
    };

    v2f s0acc = (v2f){0.f, 0.f};
    const int r0w = wave * 8;
#pragma unroll
    for (int g = 0; g < 2; ++g) {
      const int j0 = r0w + 4 * g;
      const float4* x0 = reinterpret_cast<const float4*>(&xb[(size_t)(j0 + 0) * D_]);
      const float4* x1 = reinterpret_cast<const float4*>(&xb[(size_t)(j0 + 1) * D_]);
      const float4* x2 = reinterpret_cast<const float4*>(&xb[(size_t)(j0 + 2) * D_]);
      const float4* x3 = reinterpret_cast<const float4*>(&xb[(size_t)(j0 + 3) * D_]);
      float4 xa0 = x0[2 * lane], xc0 = x0[2 * lane + 1];
      float4 xa1 = x1[2 * lane], xc1 = x1[2 * lane + 1];
      float4 xa2 = x2[2 * lane], xc2 = x2[2 * lane + 1];
      float4 xa3 = x3[2 * lane], xc3 = x3[2 * lane + 1];
      v2f p0 = row_probs(xa0, xc0);
      v2f p1 = row_probs(xa1, xc1);
      v2f p2 = row_probs(xa2, xc2);
      v2f p3 = row_probs(xa3, xc3);
      s0acc += (p0 + p1) + (p2 + p3);
      if (lane < 4) {
        *reinterpret_cast<v2f*>(&p_lds[j0 + 0][2 * lane]) = p0;
        *reinterpret_cast<v2f*>(&p_lds[j0 + 1][2 * lane]) = p1;
        *reinterpret_cast<v2f*>(&p_lds[j0 + 2][2 * lane]) = p2;
        *reinterpret_cast<v2f*>(&p_lds[j0 + 3][2 * lane]) = p3;
      }
    }
    if (lane < 4) s0sh[wave][lane] = s0acc;
  }
  __syncthreads();

  const int cslot = atomic_mode ? 0 : chunk;
  if (threadIdx.x < 4) {
    v2f s = (s0sh[0][threadIdx.x] + s0sh[1][threadIdx.x]) +
            (s0sh[2][threadIdx.x] + s0sh[3][threadIdx.x]);
    float* d0 = s0p + (size_t)(b * cstride + cslot) * K_;
    if (atomic_mode) {
      atomicAdd(d0 + threadIdx.x, s.x); atomicAdd(d0 + threadIdx.x + 4, s.y);
    } else {
      d0[threadIdx.x] = s.x; d0[threadIdx.x + 4] = s.y;
    }
  }

  // ---------------- phase 2: moments. wave owns k = {wave, wave+4} ----------
  const int q = wave;

  v2f acc0[8], acc1[8];
#pragma unroll
  for (int dj = 0; dj < 8; ++dj) { acc0[dj] = (v2f){0,0}; acc1[dj] = (v2f){0,0}; }

  const float4* xr = reinterpret_cast<const float4*>(xb);   // row stride = 128 float4
  // current pair (rows 0,1)
  float4 Aa = xr[2 * lane], Ac = xr[2 * lane + 1];
  float4 Ba = xr[128 + 2 * lane], Bc = xr[128 + 2 * lane + 1];
  v2f Ap = *reinterpret_cast<const v2f*>(&p_lds[0][2 * q]);
  v2f Bp = *reinterpret_cast<const v2f*>(&p_lds[1][2 * q]);

  for (int rp = 0; rp < ROWS_PB / 2; ++rp) {
    const int nx = (rp + 1 < ROWS_PB / 2) ? rp + 1 : rp;
    float4 nAa = xr[(2 * nx) * 128 + 2 * lane],     nAc = xr[(2 * nx) * 128 + 2 * lane + 1];
    float4 nBa = xr[(2 * nx + 1) * 128 + 2 * lane], nBc = xr[(2 * nx + 1) * 128 + 2 * lane + 1];
    v2f nAp = *reinterpret_cast<const v2f*>(&p_lds[2 * nx][2 * q]);
    v2f nBp = *reinterpret_cast<const v2f*>(&p_lds[2 * nx + 1][2 * q]);

    float xvA[8] = {Aa.x, Aa.y, Aa.z, Aa.w, Ac.x, Ac.y, Ac.z, Ac.w};
    float xvB[8] = {Ba.x, Ba.y, Ba.z, Ba.w, Bc.x, Bc.y, Bc.z, Bc.w};
    v2f A0 = (v2f){Ap.x, Ap.x}, A1 = (v2f){Ap.y, Ap.y};
    v2f B0 = (v2f){Bp.x, Bp.x}, B1 = (v2f){Bp.y, Bp.y};
#pragma unroll
    for (int dj = 0; dj < 8; ++dj) {
      v2f mA = (v2f){xvA[dj], xvA[dj] * xvA[dj]};
      v2f mB = (v2f){xvB[dj], xvB[dj] * xvB[dj]};
      acc0[dj] += mA * A0 + mB * B0;
      acc1[dj] += mA * A1 + mB * B1;
    }
    Aa = nAa; Ac = nAc; Ba = nBa; Bc = nBc; Ap = nAp; Bp = nBp;
  }

  // direct coalesced flush: k = q (acc0) and q+4 (acc1)
#pragma unroll
  for (int kk = 0; kk < 2; ++kk) {
    const int k = q + 4 * kk;
    v2f* acc = kk ? acc1 : acc0;
    float* dst = partial + (((size_t)(b * cstride + cslot) * K_ + k) * D_ + 8 * lane) * 2;
#pragma unroll
    for (int g = 0; g < 4; ++g) {
      v2f u0 = acc[2 * g];
      v2f u1 = acc[2 * g + 1];
      if (atomic_mode) {
        atomicAdd(dst + g * 4 + 0, u0.x); atomicAdd(dst + g * 4 + 1, u0.y);
        atomicAdd(dst + g * 4 + 2, u1.x); atomicAdd(dst + g * 4 + 3, u1.y);
      } else {
        float4 v; v.x = u0.x; v.y = u0.y; v.z = u1.x; v.w = u1.y;
        *reinterpret_cast<float4*>(dst + g * 4) = v;   // 16B aligned
      }
    }
  }
}

// ---------------- k2: finalize ----------------
// grid = B*32 slices, 256 thr: cq(2) x k(8) x dl(16); cq splits the chunk sum.
__global__ __launch_bounds__(256)
void k2_final(const float* __restrict__ partial, const float* __restrict__ s0p,
              const float* __restrict__ eps, float* __restrict__ out,
              int cstride, int nchunks) {
  const int b = blockIdx.x >> 5;
  const int slice = blockIdx.x & 31;
  const int tid = threadIdx.x;
  const int cq = tid >> 7;
  const int k  = (tid >> 4) & 7;
  const int dl = tid & 15;
  const int d  = slice * 16 + dl;

  __shared__ float s0sh[K_];
  __shared__ v2f red2[2][K_][16];
  __shared__ float zsh[K_][16];
  __shared__ float klsh[4];

  // wave 0: reduce S0 over chunks (8 k x 8 parts)
  if (tid < 64) {
    const int kk = tid & 7, part = tid >> 3;
    float s = 0.f;
    for (int c = part; c < nchunks; c += 8)
      s += s0p[(size_t)(b * cstride + c) * K_ + kk];
    s += __shfl_xor(s, 8, 64);
    s += __shfl_xor(s, 16, 64);
    s += __shfl_xor(s, 32, 64);
    if (tid < 8) s0sh[tid] = s;
  }

  const int half = (nchunks + 1) >> 1;
  const int cbeg = cq * half;
  const int cend = (cbeg + half < nchunks) ? (cbeg + half) : nchunks;

  const float* base = partial + (((size_t)b * cstride) * K_ + k) * D_ * 2 + d * 2;
  const size_t cstep = (size_t)K_ * D_ * 2;

  v2f s0v = (v2f){0,0}, s1v = (v2f){0,0}, s2v = (v2f){0,0}, s3v = (v2f){0,0};
  int c = cbeg;
  for (; c + 4 <= cend; c += 4) {
    s0v += *reinterpret_cast<const v2f*>(base + (size_t)c * cstep);
    s1v += *reinterpret_cast<const v2f*>(base + (size_t)(c + 1) * cstep);
    s2v += *reinterpret_cast<const v2f*>(base + (size_t)(c + 2) * cstep);
    s3v += *reinterpret_cast<const v2f*>(base + (size_t)(c + 3) * cstep);
  }
  for (; c < cend; ++c) s0v += *reinterpret_cast<const v2f*>(base + (size_t)c * cstep);
  red2[cq][k][dl] = (s0v + s1v) + (s2v + s3v);
  __syncthreads();

  float klp = 0.f;
  if (cq == 0) {
    v2f sv = red2[0][k][dl] + red2[1][k][dl];
    const float S1 = sv.x, S2 = sv.y;
    const float S0 = s0sh[k];
    float sigraw = S2 + (S0 - 2.f) * S1 * S1;
    float sig = fmaxf(sigraw, 0.f) + EPS_;
    float z = S1 + eps[((size_t)(b * K_ + k)) * D_ + d] * sqrtf(sig);
    zsh[k][dl] = z;
    klp = 1.f + logf(sig) - S1 * S1 - sigraw;
  }

  klp += __shfl_xor(klp, 1, 64);
  klp += __shfl_xor(klp, 2, 64);
  klp += __shfl_xor(klp, 4, 64);
  klp += __shfl_xor(klp, 8, 64);
  klp += __shfl_xor(klp, 16, 64);
  klp += __shfl_xor(klp, 32, 64);
  const int lane = tid & 63, wv = tid >> 6;
  if (lane == 0) klsh[wv] = klp;
  __syncthreads();

  if (tid < 16) {
    float pooled = 0.f;
#pragma unroll
    for (int kk = 0; kk < K_; ++kk) pooled += zsh[kk][tid];
    out[b * D_ + slice * 16 + tid] = pooled * 0.125f;
  }
  if (tid == 0) {
    atomicAdd(out + B_ * D_, (klsh[0] + klsh[1] + klsh[2] + klsh[3]) * (-0.5f / (B_ * K_)));
  }
}

extern "C" void kernel_launch(void* const* d_in, const int* in_sizes, int n_in,
                              void* d_out, int out_size, void* d_ws, size_t ws_size,
                              hipStream_t stream) {
  const float* x    = (const float*)d_in[0];
  const float* W    = (const float*)d_in[1];
  const float* bias = (const float*)d_in[2];
  const float* eps  = (const float*)d_in[3];
  float* out = (float*)d_out;
  float* ws  = (float*)d_ws;

  const size_t full_floats = PART_FLOATS(CHUNKS) + S0_FLOATS(CHUNKS);
  const int atomic_mode = (ws_size < full_floats * sizeof(float)) ? 1 : 0;
  const int cstride = atomic_mode ? 1 : CHUNKS;
  const int nchunks = atomic_mode ? 1 : CHUNKS;

  float* partial = ws;
  float* s0p     = partial + PART_FLOATS(cstride);

  if (atomic_mode) {
    hipMemsetAsync(partial, 0, (PART_FLOATS(1) + S0_FLOATS(1)) * sizeof(float), stream);
  }
  // out KL slot zeroed by k1 block 0 (k1 fully precedes k2 in-stream).

  k1_fused<<<B_ * CHUNKS, 256, 0, stream>>>(x, W, bias, partial, s0p, out, cstride, atomic_mode);
  k2_final<<<B_ * 32, 256, 0, stream>>>(partial, s0p, eps, out, cstride, nchunks);
}

// Round 10
// 335.889 us; speedup vs baseline: 1.0014x; 1.0014x over previous
//
#include <hip/hip_runtime.h>

// SoftClusterGaussianHead — round 10: round-8 base + DPP-shortened hops ONLY.
// B=8, N=4096, D=512, K=8.
// sigma = S2 + (S0-2)*S1^2 with S0=sum_n p, S1=sum_n p*x, S2=sum_n p*x^2.
// Phase 1: logits -> reduce-scatter to k-pairs (lane&3 -> {k,k+4}).
//   Cross-lane hops: quad_perm(xor1/xor2), row_ror4/8 (DPP, VALU-latency);
//   only xor16/xor32 are DS hops. Softmax via DPP quads. p -> LDS (1 KB).
// Phase 2: wave owns k-pair {w,w+4}, 2-row ILP + prefetch, coalesced flush.
// ws: partial[b][chunk][k][d][2] | s0p[b][chunk][k]

typedef float v2f __attribute__((ext_vector_type(2)));

#define B_ 8
#define N_ 4096
#define D_ 512
#define K_ 8
#define EPS_ 1e-6f
#define CHUNKS 128           // blocks per b
#define ROWS_PB 32           // rows per block
#define PART_FLOATS(cs) ((size_t)B_ * (cs) * K_ * D_ * 2)
#define S0_FLOATS(cs)   ((size_t)B_ * (cs) * K_)

template <int CTRL>
__device__ __forceinline__ float dppf(float v) {
  int i = __float_as_int(v);
  return __int_as_float(__builtin_amdgcn_update_dpp(i, i, CTRL, 0xF, 0xF, false));
}
#define DPP_XOR1 0xB1   // quad_perm(1,0,3,2)
#define DPP_XOR2 0x4E   // quad_perm(2,3,0,1)
#define DPP_ROR4 0x124  // row_ror:4  ((l+4)%16 — preserves l&3 class)
#define DPP_ROR8 0x128  // row_ror:8  ((l+8)%16 — preserves l&3 class)

__global__ __launch_bounds__(256, 2)
void k1_fused(const float* __restrict__ x, const float* __restrict__ W,
              const float* __restrict__ bias, float* __restrict__ partial,
              float* __restrict__ s0p, float* __restrict__ out,
              int cstride, int atomic_mode) {
#pragma clang fp contract(fast)
  const int lane = threadIdx.x & 63;
  const int wave = threadIdx.x >> 6;    // 0..3
  const int b     = blockIdx.x >> 7;
  const int chunk = blockIdx.x & 127;

  // zero the KL accumulator slot for k2 (k1 fully precedes k2 in-stream)
  if (blockIdx.x == 0 && threadIdx.x == 0) out[B_ * D_] = 0.f;

  // p_lds[row][2*kq + sel]: (p[kq], p[kq+4]) pairs, kq = 0..3
  __shared__ float p_lds[ROWS_PB][K_];   // 1 KB
  __shared__ v2f   s0sh[4][4];           // [wave][kq] = (S0_k, S0_k+4)

  const float* xb = x + ((size_t)b * N_ + (size_t)chunk * ROWS_PB) * D_;

  // ---------------- phase 1: softmax probs ----------------
  {
    // lane owns d = 8*lane .. 8*lane+7 ; wk[dj][kp] = (W[d][2kp], W[d][2kp+1])
    v2f wk[8][4];
#pragma unroll
    for (int dj = 0; dj < 8; ++dj) {
      const float4* wr = reinterpret_cast<const float4*>(&W[(8 * lane + dj) * K_]);
      float4 wa = wr[0], wb4 = wr[1];
      wk[dj][0] = (v2f){wa.x, wa.y};   wk[dj][1] = (v2f){wa.z, wa.w};
      wk[dj][2] = (v2f){wb4.x, wb4.y}; wk[dj][3] = (v2f){wb4.z, wb4.w};
    }
    const int kq = lane & 3;
    const v2f biasv2 = (v2f){bias[kq], bias[kq + 4]};
    const bool cb0 = (lane & 1) != 0;
    const bool cb1 = (lane & 2) != 0;

    // per-row: partial logits -> reduce-scatter to k-pair -> lane-local softmax
    auto row_probs = [&](float4 xa, float4 xc) -> v2f {
      float xv[8] = {xa.x, xa.y, xa.z, xa.w, xc.x, xc.y, xc.z, xc.w};
      v2f qp[4] = {(v2f){0,0},(v2f){0,0},(v2f){0,0},(v2f){0,0}};
#pragma unroll
      for (int dj = 0; dj < 8; ++dj) {
        v2f xx = (v2f){xv[dj], xv[dj]};
#pragma unroll
        for (int kp = 0; kp < 4; ++kp) qp[kp] += wk[dj][kp] * xx;
      }
      float q0=qp[0].x,q1=qp[0].y,q2=qp[1].x,q3=qp[1].y;
      float q4=qp[2].x,q5=qp[2].y,q6=qp[3].x,q7=qp[3].y;

      // stage A (xor1 via quad_perm): combine q-pairs
      float r0 = cb0 ? q0 : q1, r1 = cb0 ? q2 : q3, r2 = cb0 ? q4 : q5, r3 = cb0 ? q6 : q7;
      r0 = dppf<DPP_XOR1>(r0); r1 = dppf<DPP_XOR1>(r1);
      r2 = dppf<DPP_XOR1>(r2); r3 = dppf<DPP_XOR1>(r3);
      float a0 = (cb0 ? q1 : q0) + r0, a1 = (cb0 ? q3 : q2) + r1;
      float a2 = (cb0 ? q5 : q4) + r2, a3 = (cb0 ? q7 : q6) + r3;
      // stage B (xor2 via quad_perm): lane ends with (k=kq, k=kq+4) partial
      float s0_ = cb1 ? a0 : a1, s1_ = cb1 ? a2 : a3;
      s0_ = dppf<DPP_XOR2>(s0_); s1_ = dppf<DPP_XOR2>(s1_);
      v2f t2 = (v2f){(cb1 ? a1 : a0) + s0_, (cb1 ? a3 : a2) + s1_};
      // stage C: sum same-kq lanes. ror4+ror8 (DPP, class-preserving mod 4),
      // then cross-row xor16, cross-half xor32 (the only DS-latency hops).
      t2.x += dppf<DPP_ROR4>(t2.x); t2.y += dppf<DPP_ROR4>(t2.y);
      t2.x += dppf<DPP_ROR8>(t2.x); t2.y += dppf<DPP_ROR8>(t2.y);
      t2.x += __shfl_xor(t2.x, 16, 64); t2.y += __shfl_xor(t2.y, 16, 64);
      t2.x += __shfl_xor(t2.x, 32, 64); t2.y += __shfl_xor(t2.y, 32, 64);
      t2 += biasv2;
      // softmax over 8 k's within the quad (all DPP)
      float mx = fmaxf(t2.x, t2.y);
      mx = fmaxf(mx, dppf<DPP_XOR1>(mx));
      mx = fmaxf(mx, dppf<DPP_XOR2>(mx));
      float ex = __expf(t2.x - mx), ey = __expf(t2.y - mx);
      float se = ex + ey;
      se += dppf<DPP_XOR1>(se);
      se += dppf<DPP_XOR2>(se);
      float inv = __builtin_amdgcn_rcpf(se);
      return (v2f){ex * inv, ey * inv};
    };

    v2f s0acc = (v2f){0.f, 0.f};
    const int r0w = wave * 8;
#pragma unroll
    for (int jp = 0; jp < 4; ++jp) {
      const int j0 = r0w + 2 * jp;
      const float4* x0 = reinterpret_cast<const float4*>(&xb[(size_t)j0 * D_]);
      const float4* x1 = reinterpret_cast<const float4*>(&xb[(size_t)(j0 + 1) * D_]);
      float4 xa0 = x0[2 * lane], xc0 = x0[2 * lane + 1];
      float4 xa1 = x1[2 * lane], xc1 = x1[2 * lane + 1];
      v2f p0 = row_probs(xa0, xc0);
      v2f p1 = row_probs(xa1, xc1);
      s0acc += p0 + p1;
      if (lane < 4) {
        *reinterpret_cast<v2f*>(&p_lds[j0][2 * lane])     = p0;
        *reinterpret_cast<v2f*>(&p_lds[j0 + 1][2 * lane]) = p1;
      }
    }
    if (lane < 4) s0sh[wave][lane] = s0acc;
  }
  __syncthreads();

  const int cslot = atomic_mode ? 0 : chunk;
  if (threadIdx.x < 4) {
    v2f s = (s0sh[0][threadIdx.x] + s0sh[1][threadIdx.x]) +
            (s0sh[2][threadIdx.x] + s0sh[3][threadIdx.x]);
    float* d0 = s0p + (size_t)(b * cstride + cslot) * K_;
    if (atomic_mode) {
      atomicAdd(d0 + threadIdx.x, s.x); atomicAdd(d0 + threadIdx.x + 4, s.y);
    } else {
      d0[threadIdx.x] = s.x; d0[threadIdx.x + 4] = s.y;
    }
  }

  // ---------------- phase 2: moments. wave owns k = {wave, wave+4} ----------
  const int q = wave;

  v2f acc0[8], acc1[8];
#pragma unroll
  for (int dj = 0; dj < 8; ++dj) { acc0[dj] = (v2f){0,0}; acc1[dj] = (v2f){0,0}; }

  const float4* xr = reinterpret_cast<const float4*>(xb);   // row stride = 128 float4
  // current pair (rows 0,1)
  float4 Aa = xr[2 * lane], Ac = xr[2 * lane + 1];
  float4 Ba = xr[128 + 2 * lane], Bc = xr[128 + 2 * lane + 1];
  v2f Ap = *reinterpret_cast<const v2f*>(&p_lds[0][2 * q]);
  v2f Bp = *reinterpret_cast<const v2f*>(&p_lds[1][2 * q]);

  for (int rp = 0; rp < ROWS_PB / 2; ++rp) {
    const int nx = (rp + 1 < ROWS_PB / 2) ? rp + 1 : rp;
    float4 nAa = xr[(2 * nx) * 128 + 2 * lane],     nAc = xr[(2 * nx) * 128 + 2 * lane + 1];
    float4 nBa = xr[(2 * nx + 1) * 128 + 2 * lane], nBc = xr[(2 * nx + 1) * 128 + 2 * lane + 1];
    v2f nAp = *reinterpret_cast<const v2f*>(&p_lds[2 * nx][2 * q]);
    v2f nBp = *reinterpret_cast<const v2f*>(&p_lds[2 * nx + 1][2 * q]);

    float xvA[8] = {Aa.x, Aa.y, Aa.z, Aa.w, Ac.x, Ac.y, Ac.z, Ac.w};
    float xvB[8] = {Ba.x, Ba.y, Ba.z, Ba.w, Bc.x, Bc.y, Bc.z, Bc.w};
    v2f A0 = (v2f){Ap.x, Ap.x}, A1 = (v2f){Ap.y, Ap.y};
    v2f B0 = (v2f){Bp.x, Bp.x}, B1 = (v2f){Bp.y, Bp.y};
#pragma unroll
    for (int dj = 0; dj < 8; ++dj) {
      v2f mA = (v2f){xvA[dj], xvA[dj] * xvA[dj]};
      v2f mB = (v2f){xvB[dj], xvB[dj] * xvB[dj]};
      acc0[dj] += mA * A0 + mB * B0;
      acc1[dj] += mA * A1 + mB * B1;
    }
    Aa = nAa; Ac = nAc; Ba = nBa; Bc = nBc; Ap = nAp; Bp = nBp;
  }

  // direct coalesced flush: k = q (acc0) and q+4 (acc1)
#pragma unroll
  for (int kk = 0; kk < 2; ++kk) {
    const int k = q + 4 * kk;
    v2f* acc = kk ? acc1 : acc0;
    float* dst = partial + (((size_t)(b * cstride + cslot) * K_ + k) * D_ + 8 * lane) * 2;
#pragma unroll
    for (int g = 0; g < 4; ++g) {
      v2f u0 = acc[2 * g];
      v2f u1 = acc[2 * g + 1];
      if (atomic_mode) {
        atomicAdd(dst + g * 4 + 0, u0.x); atomicAdd(dst + g * 4 + 1, u0.y);
        atomicAdd(dst + g * 4 + 2, u1.x); atomicAdd(dst + g * 4 + 3, u1.y);
      } else {
        float4 v; v.x = u0.x; v.y = u0.y; v.z = u1.x; v.w = u1.y;
        *reinterpret_cast<float4*>(dst + g * 4) = v;   // 16B aligned
      }
    }
  }
}

// ---------------- k2: finalize ----------------
// grid = B*32 slices, 256 thr: cq(2) x k(8) x dl(16); cq splits the chunk sum.
__global__ __launch_bounds__(256)
void k2_final(const float* __restrict__ partial, const float* __restrict__ s0p,
              const float* __restrict__ eps, float* __restrict__ out,
              int cstride, int nchunks) {
  const int b = blockIdx.x >> 5;
  const int slice = blockIdx.x & 31;
  const int tid = threadIdx.x;
  const int cq = tid >> 7;
  const int k  = (tid >> 4) & 7;
  const int dl = tid & 15;
  const int d  = slice * 16 + dl;

  __shared__ float s0sh[K_];
  __shared__ v2f red2[2][K_][16];
  __shared__ float zsh[K_][16];
  __shared__ float klsh[4];

  // wave 0: reduce S0 over chunks (8 k x 8 parts)
  if (tid < 64) {
    const int kk = tid & 7, part = tid >> 3;
    float s = 0.f;
    for (int c = part; c < nchunks; c += 8)
      s += s0p[(size_t)(b * cstride + c) * K_ + kk];
    s += __shfl_xor(s, 8, 64);
    s += __shfl_xor(s, 16, 64);
    s += __shfl_xor(s, 32, 64);
    if (tid < 8) s0sh[tid] = s;
  }

  const int half = (nchunks + 1) >> 1;
  const int cbeg = cq * half;
  const int cend = (cbeg + half < nchunks) ? (cbeg + half) : nchunks;

  const float* base = partial + (((size_t)b * cstride) * K_ + k) * D_ * 2 + d * 2;
  const size_t cstep = (size_t)K_ * D_ * 2;

  v2f s0v = (v2f){0,0}, s1v = (v2f){0,0}, s2v = (v2f){0,0}, s3v = (v2f){0,0};
  int c = cbeg;
  for (; c + 4 <= cend; c += 4) {
    s0v += *reinterpret_cast<const v2f*>(base + (size_t)c * cstep);
    s1v += *reinterpret_cast<const v2f*>(base + (size_t)(c + 1) * cstep);
    s2v += *reinterpret_cast<const v2f*>(base + (size_t)(c + 2) * cstep);
    s3v += *reinterpret_cast<const v2f*>(base + (size_t)(c + 3) * cstep);
  }
  for (; c < cend; ++c) s0v += *reinterpret_cast<const v2f*>(base + (size_t)c * cstep);
  red2[cq][k][dl] = (s0v + s1v) + (s2v + s3v);
  __syncthreads();

  float klp = 0.f;
  if (cq == 0) {
    v2f sv = red2[0][k][dl] + red2[1][k][dl];
    const float S1 = sv.x, S2 = sv.y;
    const float S0 = s0sh[k];
    float sigraw = S2 + (S0 - 2.f) * S1 * S1;
    float sig = fmaxf(sigraw, 0.f) + EPS_;
    float z = S1 + eps[((size_t)(b * K_ + k)) * D_ + d] * sqrtf(sig);
    zsh[k][dl] = z;
    klp = 1.f + logf(sig) - S1 * S1 - sigraw;
  }

  klp += __shfl_xor(klp, 1, 64);
  klp += __shfl_xor(klp, 2, 64);
  klp += __shfl_xor(klp, 4, 64);
  klp += __shfl_xor(klp, 8, 64);
  klp += __shfl_xor(klp, 16, 64);
  klp += __shfl_xor(klp, 32, 64);
  const int lane = tid & 63, wv = tid >> 6;
  if (lane == 0) klsh[wv] = klp;
  __syncthreads();

  if (tid < 16) {
    float pooled = 0.f;
#pragma unroll
    for (int kk = 0; kk < K_; ++kk) pooled += zsh[kk][tid];
    out[b * D_ + slice * 16 + tid] = pooled * 0.125f;
  }
  if (tid == 0) {
    atomicAdd(out + B_ * D_, (klsh[0] + klsh[1] + klsh[2] + klsh[3]) * (-0.5f / (B_ * K_)));
  }
}

extern "C" void kernel_launch(void* const* d_in, const int* in_sizes, int n_in,
                              void* d_out, int out_size, void* d_ws, size_t ws_size,
                              hipStream_t stream) {
  const float* x    = (const float*)d_in[0];
  const float* W    = (const float*)d_in[1];
  const float* bias = (const float*)d_in[2];
  const float* eps  = (const float*)d_in[3];
  float* out = (float*)d_out;
  float* ws  = (float*)d_ws;

  const size_t full_floats = PART_FLOATS(CHUNKS) + S0_FLOATS(CHUNKS);
  const int atomic_mode = (ws_size < full_floats * sizeof(float)) ? 1 : 0;
  const int cstride = atomic_mode ? 1 : CHUNKS;
  const int nchunks = atomic_mode ? 1 : CHUNKS;

  float* partial = ws;
  float* s0p     = partial + PART_FLOATS(cstride);

  if (atomic_mode) {
    hipMemsetAsync(partial, 0, (PART_FLOATS(1) + S0_FLOATS(1)) * sizeof(float), stream);
  }
  // out KL slot zeroed by k1 block 0 (k1 fully precedes k2 in-stream).

  k1_fused<<<B_ * CHUNKS, 256, 0, stream>>>(x, W, bias, partial, s0p, out, cstride, atomic_mode);
  k2_final<<<B_ * 32, 256, 0, stream>>>(partial, s0p, eps, out, cstride, nchunks);
}